// Round 1
// baseline (89.152 us; speedup 1.0000x reference)
//
#include <hip/hip_runtime.h>
#include <float.h>

#define NN 4
#define CC 2
#define HH 256
#define WW 256
#define OO 4
#define KHH 5
#define KWW 5
#define HO 252
#define WO 252

#define TW 32
#define TH 8
#define IW (TW + KWW - 1)  // 36
#define IH (TH + KHH - 1)  // 12

__global__ __launch_bounds__(256) void k_minmax_partial(const float* __restrict__ in,
                                                        float* __restrict__ ws) {
    const int n4 = (NN * CC * HH * WW) / 4;  // 131072
    float vmin = FLT_MAX, vmax = -FLT_MAX;
    const float4* in4 = (const float4*)in;
    for (int i = blockIdx.x * blockDim.x + threadIdx.x; i < n4; i += gridDim.x * blockDim.x) {
        float4 v = in4[i];
        vmin = fminf(vmin, fminf(fminf(v.x, v.y), fminf(v.z, v.w)));
        vmax = fmaxf(vmax, fmaxf(fmaxf(v.x, v.y), fmaxf(v.z, v.w)));
    }
    #pragma unroll
    for (int off = 32; off > 0; off >>= 1) {
        vmin = fminf(vmin, __shfl_down(vmin, off));
        vmax = fmaxf(vmax, __shfl_down(vmax, off));
    }
    __shared__ float smin[4], smax[4];
    const int wave = threadIdx.x >> 6, lane = threadIdx.x & 63;
    if (lane == 0) { smin[wave] = vmin; smax[wave] = vmax; }
    __syncthreads();
    if (threadIdx.x == 0) {
        float m0 = fminf(fminf(smin[0], smin[1]), fminf(smin[2], smin[3]));
        float m1 = fmaxf(fmaxf(smax[0], smax[1]), fmaxf(smax[2], smax[3]));
        ws[2 * blockIdx.x]     = m0;
        ws[2 * blockIdx.x + 1] = m1;
    }
}

__global__ __launch_bounds__(256) void k_minmax_final(float* __restrict__ ws) {
    // 256 threads read the 256 (min,max) pairs written by k_minmax_partial.
    float vmin = ws[2 * threadIdx.x];
    float vmax = ws[2 * threadIdx.x + 1];
    #pragma unroll
    for (int off = 32; off > 0; off >>= 1) {
        vmin = fminf(vmin, __shfl_down(vmin, off));
        vmax = fmaxf(vmax, __shfl_down(vmax, off));
    }
    __shared__ float smin[4], smax[4];
    const int wave = threadIdx.x >> 6, lane = threadIdx.x & 63;
    if (lane == 0) { smin[wave] = vmin; smax[wave] = vmax; }
    __syncthreads();
    if (threadIdx.x == 0) {
        float m0 = fminf(fminf(smin[0], smin[1]), fminf(smin[2], smin[3]));
        float m1 = fmaxf(fmaxf(smax[0], smax[1]), fmaxf(smax[2], smax[3]));
        ws[512] = m0;
        ws[513] = m1;
    }
}

__global__ __launch_bounds__(256) void k_lmorph(const float* __restrict__ in,
                                                const float* __restrict__ filt,
                                                const float* __restrict__ p,
                                                const float* __restrict__ ws,
                                                float* __restrict__ out) {
    __shared__ float xs[CC * IH * IW];          // 864 floats, prescaled x in [1,2]
    __shared__ float fs[OO * CC * KHH * KWW];   // 200 floats

    const int tid = threadIdx.x;
    const int bx = blockIdx.x, by = blockIdx.y, n = blockIdx.z;

    const float smin = ws[512];
    const float inv  = 1.0f / (ws[513] - smin);

    if (tid < OO * CC * KHH * KWW) fs[tid] = filt[tid];

    const int y0 = by * TH, x0 = bx * TW;
    for (int i = tid; i < CC * IH * IW; i += 256) {
        int c   = i / (IH * IW);
        int rem = i - c * (IH * IW);
        int r   = rem / IW;
        int col = rem - r * IW;
        int gy = y0 + r, gx = x0 + col;
        float v = 0.0f;
        if (gy < HH && gx < WW) v = in[((n * CC + c) * HH + gy) * WW + gx];
        xs[i] = 1.0f + (v - smin) * inv;
    }
    __syncthreads();

    const int tx = tid & 31, ty = tid >> 5;
    const int ox = x0 + tx, oy = y0 + ty;
    if (ox >= WO || oy >= HO) return;

    float pv[OO][CC];
    #pragma unroll
    for (int o = 0; o < OO; ++o)
        #pragma unroll
        for (int c = 0; c < CC; ++c)
            pv[o][c] = p[o * CC + c];

    float num[OO] = {0.f, 0.f, 0.f, 0.f};
    float den[OO] = {0.f, 0.f, 0.f, 0.f};

    for (int c = 0; c < CC; ++c) {
        #pragma unroll
        for (int kh = 0; kh < KHH; ++kh) {
            #pragma unroll
            for (int kw = 0; kw < KWW; ++kw) {
                const float xv = xs[(c * IH + (ty + kh)) * IW + (tx + kw)];
                #pragma unroll
                for (int o = 0; o < OO; ++o) {
                    const float t  = xv + fs[(o * CC + c) * (KHH * KWW) + kh * KWW + kw];
                    const float lt = __logf(t);             // t >= 1, safe
                    const float w  = __expf(pv[o][c] * lt); // t^p
                    num[o] = fmaf(w, t, num[o]);            // t^(p+1)
                    den[o] += w;
                }
            }
        }
    }

    #pragma unroll
    for (int o = 0; o < OO; ++o) {
        out[((n * OO + o) * HO + oy) * WO + ox] = num[o] / den[o];
    }
}

extern "C" void kernel_launch(void* const* d_in, const int* in_sizes, int n_in,
                              void* d_out, int out_size, void* d_ws, size_t ws_size,
                              hipStream_t stream) {
    const float* in   = (const float*)d_in[0];
    const float* filt = (const float*)d_in[1];
    const float* p    = (const float*)d_in[2];
    float* out = (float*)d_out;
    float* ws  = (float*)d_ws;

    k_minmax_partial<<<256, 256, 0, stream>>>(in, ws);
    k_minmax_final<<<1, 256, 0, stream>>>(ws);

    dim3 grid((WO + TW - 1) / TW, (HO + TH - 1) / TH, NN);  // (8, 32, 4)
    k_lmorph<<<grid, 256, 0, stream>>>(in, filt, p, ws, out);
}

// Round 2
// 77.649 us; speedup vs baseline: 1.1481x; 1.1481x over previous
//
#include <hip/hip_runtime.h>
#include <float.h>

#define NN 4
#define CC 2
#define HH 256
#define WW 256
#define OO 4
#define KHH 5
#define KWW 5
#define HO 252
#define WO 252

#define TW 32
#define TH 8
#define IW (TW + KWW - 1)  // 36
#define IH (TH + KHH - 1)  // 12
#define NPART 64           // partial min/max pairs (one reducing wave covers 64 lanes)

__global__ __launch_bounds__(256) void k_minmax_partial(const float* __restrict__ in,
                                                        float* __restrict__ ws) {
    const int n4 = (NN * CC * HH * WW) / 4;  // 131072 float4s
    float vmin = FLT_MAX, vmax = -FLT_MAX;
    const float4* in4 = (const float4*)in;
    for (int i = blockIdx.x * 256 + threadIdx.x; i < n4; i += NPART * 256) {
        float4 v = in4[i];
        vmin = fminf(vmin, fminf(fminf(v.x, v.y), fminf(v.z, v.w)));
        vmax = fmaxf(vmax, fmaxf(fmaxf(v.x, v.y), fmaxf(v.z, v.w)));
    }
    #pragma unroll
    for (int off = 32; off > 0; off >>= 1) {
        vmin = fminf(vmin, __shfl_down(vmin, off));
        vmax = fmaxf(vmax, __shfl_down(vmax, off));
    }
    __shared__ float smin[4], smax[4];
    const int wave = threadIdx.x >> 6, lane = threadIdx.x & 63;
    if (lane == 0) { smin[wave] = vmin; smax[wave] = vmax; }
    __syncthreads();
    if (threadIdx.x == 0) {
        ws[2 * blockIdx.x]     = fminf(fminf(smin[0], smin[1]), fminf(smin[2], smin[3]));
        ws[2 * blockIdx.x + 1] = fmaxf(fmaxf(smax[0], smax[1]), fmaxf(smax[2], smax[3]));
    }
}

__global__ __launch_bounds__(256) void k_lmorph(const float* __restrict__ in,
                                                const float* __restrict__ filt,
                                                const float* __restrict__ p,
                                                const float* __restrict__ ws,
                                                float* __restrict__ out) {
    // ---- phase 0: every wave redundantly reduces the 64 partial (min,max) pairs.
    // No LDS, no extra __syncthreads: lane l holds pair l, butterfly over 64 lanes.
    const int lane = threadIdx.x & 63;
    float vmin = ws[2 * lane];
    float vmax = ws[2 * lane + 1];
    #pragma unroll
    for (int off = 1; off < 64; off <<= 1) {
        vmin = fminf(vmin, __shfl_xor(vmin, off));
        vmax = fmaxf(vmax, __shfl_xor(vmax, off));
    }
    const float gmin = vmin;
    const float inv  = 1.0f / (vmax - vmin);

    // ---- phase 1: stage prescaled input patch (x in [1,2]) into LDS
    __shared__ float xs[CC * IH * IW];  // 864 floats
    const int tid = threadIdx.x;
    const int n = blockIdx.z;
    const int y0 = blockIdx.y * TH, x0 = blockIdx.x * TW;

    for (int i = tid; i < CC * IH * IW; i += 256) {
        int c   = i / (IH * IW);
        int rem = i - c * (IH * IW);
        int r   = rem / IW;
        int col = rem - r * IW;
        int gy = y0 + r, gx = x0 + col;
        float v = 0.0f;
        if (gy < HH && gx < WW) v = in[((n * CC + c) * HH + gy) * WW + gx];
        xs[i] = 1.0f + (v - gmin) * inv;
    }
    __syncthreads();

    const int tx = tid & 31, ty = tid >> 5;
    const int ox = x0 + tx, oy = y0 + ty;
    if (ox >= WO || oy >= HO) return;

    // p * ln2, hoisted: w = t^p = exp(p*ln2 * log2(t)) — 2 trans + 2 muls per term.
    float pl2[OO][CC];
    #pragma unroll
    for (int o = 0; o < OO; ++o)
        #pragma unroll
        for (int c = 0; c < CC; ++c)
            pl2[o][c] = p[o * CC + c] * 0.6931471805599453f;  // uniform -> s_load

    float num[OO] = {0.f, 0.f, 0.f, 0.f};
    float den[OO] = {0.f, 0.f, 0.f, 0.f};

    #pragma unroll
    for (int c = 0; c < CC; ++c) {
        // cache the 5x5 window in VGPRs once; reuse across the 4 output channels
        float xv[KHH][KWW];
        #pragma unroll
        for (int kh = 0; kh < KHH; ++kh)
            #pragma unroll
            for (int kw = 0; kw < KWW; ++kw)
                xv[kh][kw] = xs[(c * IH + (ty + kh)) * IW + (tx + kw)];

        #pragma unroll
        for (int o = 0; o < OO; ++o) {
            const float pc = pl2[o][c];
            #pragma unroll
            for (int kh = 0; kh < KHH; ++kh) {
                #pragma unroll
                for (int kw = 0; kw < KWW; ++kw) {
                    // filt index is compile-time uniform -> scalar load (no LDS/VMEM per lane)
                    const float t  = xv[kh][kw] + filt[((o * CC + c) * KHH + kh) * KWW + kw];
                    const float lt = __log2f(t);         // t >= 1, v_log_f32
                    const float w  = __expf(pc * lt);    // 2^(p*log2 t)
                    num[o] = fmaf(w, t, num[o]);
                    den[o] += w;
                }
            }
        }
    }

    #pragma unroll
    for (int o = 0; o < OO; ++o) {
        out[((n * OO + o) * HO + oy) * WO + ox] = num[o] / den[o];
    }
}

extern "C" void kernel_launch(void* const* d_in, const int* in_sizes, int n_in,
                              void* d_out, int out_size, void* d_ws, size_t ws_size,
                              hipStream_t stream) {
    const float* in   = (const float*)d_in[0];
    const float* filt = (const float*)d_in[1];
    const float* p    = (const float*)d_in[2];
    float* out = (float*)d_out;
    float* ws  = (float*)d_ws;

    k_minmax_partial<<<NPART, 256, 0, stream>>>(in, ws);

    dim3 grid((WO + TW - 1) / TW, (HO + TH - 1) / TH, NN);  // (8, 32, 4)
    k_lmorph<<<grid, 256, 0, stream>>>(in, filt, p, ws, out);
}

// Round 3
// 76.546 us; speedup vs baseline: 1.1647x; 1.0144x over previous
//
#include <hip/hip_runtime.h>
#include <float.h>

#define NN 4
#define CC 2
#define HH 256
#define WW 256
#define OO 4
#define KHH 5
#define KWW 5
#define HO 252
#define WO 252

#define TW 32
#define TH 8
#define IW (TW + KWW - 1)  // 36
#define IH (TH + KHH - 1)  // 12
#define NPART 64           // partial min/max pairs (one reducing wave covers 64 lanes)

__global__ __launch_bounds__(256) void k_minmax_partial(const float* __restrict__ in,
                                                        float* __restrict__ ws) {
    const int n4 = (NN * CC * HH * WW) / 4;  // 131072 float4s
    float vmin = FLT_MAX, vmax = -FLT_MAX;
    const float4* in4 = (const float4*)in;
    for (int i = blockIdx.x * 256 + threadIdx.x; i < n4; i += NPART * 256) {
        float4 v = in4[i];
        vmin = fminf(vmin, fminf(fminf(v.x, v.y), fminf(v.z, v.w)));
        vmax = fmaxf(vmax, fmaxf(fmaxf(v.x, v.y), fmaxf(v.z, v.w)));
    }
    #pragma unroll
    for (int off = 32; off > 0; off >>= 1) {
        vmin = fminf(vmin, __shfl_down(vmin, off));
        vmax = fmaxf(vmax, __shfl_down(vmax, off));
    }
    __shared__ float smin[4], smax[4];
    const int wave = threadIdx.x >> 6, lane = threadIdx.x & 63;
    if (lane == 0) { smin[wave] = vmin; smax[wave] = vmax; }
    __syncthreads();
    if (threadIdx.x == 0) {
        ws[2 * blockIdx.x]     = fminf(fminf(smin[0], smin[1]), fminf(smin[2], smin[3]));
        ws[2 * blockIdx.x + 1] = fmaxf(fmaxf(smax[0], smax[1]), fmaxf(smax[2], smax[3]));
    }
}

__global__ __launch_bounds__(256) void k_lmorph(const float* __restrict__ in,
                                                const float* __restrict__ filt,
                                                const float* __restrict__ p,
                                                const float* __restrict__ ws,
                                                float* __restrict__ out) {
    // ---- phase 0: every wave redundantly reduces the 64 partial (min,max) pairs.
    const int lane = threadIdx.x & 63;
    float vmin = ws[2 * lane];
    float vmax = ws[2 * lane + 1];
    #pragma unroll
    for (int off = 1; off < 64; off <<= 1) {
        vmin = fminf(vmin, __shfl_xor(vmin, off));
        vmax = fmaxf(vmax, __shfl_xor(vmax, off));
    }
    const float gmin = vmin;
    const float inv  = 1.0f / (vmax - vmin);

    // ---- phase 1: stage prescaled input patch (x in [1,2]) into LDS
    __shared__ float xs[CC * IH * IW];  // 864 floats
    const int tid = threadIdx.x;
    const int n = blockIdx.z;
    const int y0 = blockIdx.y * TH, x0 = blockIdx.x * TW;

    for (int i = tid; i < CC * IH * IW; i += 256) {
        int c   = i / (IH * IW);
        int rem = i - c * (IH * IW);
        int r   = rem / IW;
        int col = rem - r * IW;
        int gy = y0 + r, gx = x0 + col;
        float v = 0.0f;
        if (gy < HH && gx < WW) v = in[((n * CC + c) * HH + gy) * WW + gx];
        xs[i] = 1.0f + (v - gmin) * inv;
    }
    __syncthreads();

    const int tx = tid & 31, ty = tid >> 5;
    const int ox = x0 + tx, oy = y0 + ty;
    if (ox >= WO || oy >= HO) return;

    // t^p = exp(u), u = q*log2(t), q = p*ln2, |u| <= ~0.3.
    // Cubic: e = 1 + lt*(a1 + lt*(a2 + lt*a3)) with a1=q, a2=q^2/2, a3=q^3/6
    // -> per term: NO u-mul, just 3 fma in lt. Max rel err ~2.6e-4 (u^4/24).
    float a1[OO][CC], a2[OO][CC], a3[OO][CC];
    #pragma unroll
    for (int o = 0; o < OO; ++o)
        #pragma unroll
        for (int c = 0; c < CC; ++c) {
            const float q = p[o * CC + c] * 0.6931471805599453f;  // uniform -> s_load
            a1[o][c] = q;
            a2[o][c] = 0.5f * q * q;
            a3[o][c] = (1.0f / 6.0f) * q * q * q;
        }

    float num[OO] = {0.f, 0.f, 0.f, 0.f};
    float den[OO] = {0.f, 0.f, 0.f, 0.f};

    #pragma unroll
    for (int c = 0; c < CC; ++c) {
        // cache the 5x5 window in VGPRs once; reuse across the 4 output channels
        float xv[KHH][KWW];
        #pragma unroll
        for (int kh = 0; kh < KHH; ++kh)
            #pragma unroll
            for (int kw = 0; kw < KWW; ++kw)
                xv[kh][kw] = xs[(c * IH + (ty + kh)) * IW + (tx + kw)];

        #pragma unroll
        for (int o = 0; o < OO; ++o) {
            const float c1 = a1[o][c], c2 = a2[o][c], c3 = a3[o][c];
            #pragma unroll
            for (int kh = 0; kh < KHH; ++kh) {
                #pragma unroll
                for (int kw = 0; kw < KWW; ++kw) {
                    const float t  = xv[kh][kw] + filt[((o * CC + c) * KHH + kh) * KWW + kw];
                    const float lt = __log2f(t);          // v_log_f32, t >= 1
                    float h = fmaf(lt, c3, c2);
                    h = fmaf(lt, h, c1);
                    const float e = fmaf(lt, h, 1.0f);    // ~t^p
                    num[o] = fmaf(e, t, num[o]);          // ~t^(p+1)
                    den[o] += e;
                }
            }
        }
    }

    #pragma unroll
    for (int o = 0; o < OO; ++o) {
        const float r = __builtin_amdgcn_rcpf(den[o]);    // v_rcp_f32, den ~ 50..200
        out[((n * OO + o) * HO + oy) * WO + ox] = num[o] * r;
    }
}

extern "C" void kernel_launch(void* const* d_in, const int* in_sizes, int n_in,
                              void* d_out, int out_size, void* d_ws, size_t ws_size,
                              hipStream_t stream) {
    const float* in   = (const float*)d_in[0];
    const float* filt = (const float*)d_in[1];
    const float* p    = (const float*)d_in[2];
    float* out = (float*)d_out;
    float* ws  = (float*)d_ws;

    k_minmax_partial<<<NPART, 256, 0, stream>>>(in, ws);

    dim3 grid((WO + TW - 1) / TW, (HO + TH - 1) / TH, NN);  // (8, 32, 4)
    k_lmorph<<<grid, 256, 0, stream>>>(in, filt, p, ws, out);
}